// Round 2
// baseline (135.229 us; speedup 1.0000x reference)
//
#include <hip/hip_runtime.h>

#define HH 512
#define WW 512
#define NB 4            // batch
#define NC 3            // channels
#define NK 33           // histogram grid points
#define SPC 0.0625f     // 2/32
#define REP 8           // global accumulator replicas (atomic decontention)

// workspace layout, in 4-byte words:
//   [0 .. 31]                 int   bbox[2][NB][4]   {ymin,ymax,xmin,xmax} raw
//   [32 .. 32+19008)          float num[REP][2][NB][3][NC][NK]
//   [CNT_OFF .. +192)         int   cnt[REP][2][NB][3]
#define BBOX_OFF 0
#define NUM_OFF  32
#define GRP_SZ   (3*NC*NK)                      // 297
#define NUM_SZ   (REP*2*NB*GRP_SZ)              // 19008
#define CNT_OFF  (NUM_OFF + NUM_SZ)             // 19040
#define CNT_SZ   (REP*2*NB*3)                   // 192
#define WS_TOTAL (CNT_OFF + CNT_SZ)             // 19232 words (~77 KB)

__global__ void k_init(int* wsi, float* wsf) {
    int i = blockIdx.x * blockDim.x + threadIdx.x;
    for (; i < WS_TOTAL; i += gridDim.x * blockDim.x) {
        if (i < NUM_OFF) {
            int v = i & 3;  // 0:ymin 1:ymax 2:xmin 3:xmax
            wsi[i] = (v == 0) ? HH : (v == 1) ? -1 : (v == 2) ? WW : -1;
        } else if (i < CNT_OFF) {
            wsf[i] = 0.0f;
        } else {
            wsi[i] = 0;
        }
    }
}

#define BBOX_CH 64
__global__ void k_bbox(const int* __restrict__ seg_gen,
                       const int* __restrict__ seg_real,
                       int* wsi) {
    int bid = blockIdx.x;
    int map = bid / (NB * BBOX_CH);
    int rem = bid % (NB * BBOX_CH);
    int b = rem / BBOX_CH;
    int chunk = rem % BBOX_CH;
    const int* seg = (map == 0 ? seg_gen : seg_real) + b * HH * WW;
    const int PIX = HH * WW / BBOX_CH;       // 4096
    int base = chunk * PIX;
    int tid = (int)threadIdx.x;

    int ymin = HH, ymax = -1, xmin = WW, xmax = -1;
    #pragma unroll
    for (int it = 0; it < PIX / (256 * 4); ++it) {       // 4 iters, 4 px each
        int p0 = base + (it * 256 + tid) * 4;
        int4 s4 = *(const int4*)&seg[p0];
        int h = p0 >> 9;
        int w0 = p0 & (WW - 1);
        int sv[4] = {s4.x, s4.y, s4.z, s4.w};
        #pragma unroll
        for (int j = 0; j < 4; ++j) {
            int s = sv[j];
            if (s == 4 || s == 5) {
                ymin = min(ymin, h); ymax = max(ymax, h);
                xmin = min(xmin, w0 + j); xmax = max(xmax, w0 + j);
            }
        }
    }
    __shared__ int sy0[256], sy1[256], sx0[256], sx1[256];
    sy0[tid] = ymin; sy1[tid] = ymax; sx0[tid] = xmin; sx1[tid] = xmax;
    __syncthreads();
    for (int off = 128; off > 0; off >>= 1) {
        if (tid < off) {
            sy0[tid] = min(sy0[tid], sy0[tid + off]);
            sy1[tid] = max(sy1[tid], sy1[tid + off]);
            sx0[tid] = min(sx0[tid], sx0[tid + off]);
            sx1[tid] = max(sx1[tid], sx1[tid + off]);
        }
        __syncthreads();
    }
    if (tid == 0) {
        int* bb = wsi + BBOX_OFF + (map * NB + b) * 4;
        atomicMin(&bb[0], sy0[0]);
        atomicMax(&bb[1], sy1[0]);
        atomicMin(&bb[2], sx0[0]);
        atomicMax(&bb[3], sx1[0]);
    }
}

#define HIST_CH 256
__global__ void k_hist(const float* __restrict__ gen,
                       const float* __restrict__ realv,
                       const int* __restrict__ seg_gen,
                       const int* __restrict__ seg_real,
                       int* wsi, float* wsf) {
    int bid = blockIdx.x;
    int map = bid / (NB * HIST_CH);
    int rem = bid % (NB * HIST_CH);
    int b = rem / HIST_CH;
    int chunk = rem % HIST_CH;
    const float* img = (map == 0 ? gen : realv);
    const int* seg = (map == 0 ? seg_gen : seg_real) + b * HH * WW;
    int tid = (int)threadIdx.x;

    __shared__ float hist[GRP_SZ];   // [r][c][k], 297 floats
    __shared__ int scnt[3];
    for (int i = tid; i < GRP_SZ; i += 256) hist[i] = 0.0f;
    if (tid < 3) scnt[tid] = 0;

    // padded eye bbox (replicates reference, incl. the double-pad quirk)
    const int* bb = wsi + BBOX_OFF + (map * NB + b) * 4;
    int ymin0 = bb[0], ymax0 = bb[1], xmin0 = bb[2], xmax0 = bb[3];
    bool has = (ymax0 >= 0);
    int pady = (int)(0.15f * (float)(ymax0 - ymin0));
    int padx = (int)(0.15f * (float)(xmax0 - xmin0));
    int ymin = max(0, ymin0 - pady);
    int ymax = min(HH, ymax0 + pady);
    int xmin = max(0, xmin0 - padx);
    int xmax = min(WW, xmax0 + padx);
    ymax = min(HH - 1, ymax + pady);
    xmax = min(WW - 1, xmax + padx);
    __syncthreads();

    const int PIX = HH * WW / HIST_CH;    // 1024, 4 px/thread
    int p0 = chunk * PIX + tid * 4;
    int4 s4 = *(const int4*)&seg[p0];
    int h = p0 >> 9;                      // same row for all 4 (p0 % 4 == 0)
    int w0 = p0 & (WW - 1);
    bool eyerow = has & (h >= ymin) & (h < ymax);

    bool lips[4], face[4], eye[4];
    int sv[4] = {s4.x, s4.y, s4.z, s4.w};
    int cl = 0, cf = 0, ce = 0;
    bool any = false;
    #pragma unroll
    for (int j = 0; j < 4; ++j) {
        int s = sv[j];
        lips[j] = (s == 11) | (s == 12);
        face[j] = (s == 1);
        eye[j]  = eyerow & ((w0 + j) >= xmin) & ((w0 + j) < xmax);
        cl += lips[j]; cf += face[j]; ce += eye[j];
        any |= lips[j] | face[j] | eye[j];
    }

    if (any) {
        #pragma unroll
        for (int c = 0; c < NC; ++c) {
            float4 v = *(const float4*)&img[((b * NC + c) << 18) + p0];
            float xv[4] = {v.x, v.y, v.z, v.w};
            #pragma unroll
            for (int j = 0; j < 4; ++j) {
                if (!(lips[j] | face[j] | eye[j])) continue;
                float x = xv[j];
                float t = (x + 1.0f) * 16.0f;
                int k0 = (int)floorf(t);
                k0 = min(max(k0, 0), NK - 1);
                float g0 = -1.0f + SPC * (float)k0;
                float c0 = fmaxf(SPC - fabsf(x - g0), 0.0f);
                float c1 = fmaxf(SPC - fabsf(x - (g0 + SPC)), 0.0f);
                bool two = (k0 < NK - 1);
                if (lips[j]) {
                    atomicAdd(&hist[0 * NC * NK + c * NK + k0], c0);
                    if (two) atomicAdd(&hist[0 * NC * NK + c * NK + k0 + 1], c1);
                }
                if (face[j]) {
                    atomicAdd(&hist[1 * NC * NK + c * NK + k0], c0);
                    if (two) atomicAdd(&hist[1 * NC * NK + c * NK + k0 + 1], c1);
                }
                if (eye[j]) {
                    atomicAdd(&hist[2 * NC * NK + c * NK + k0], c0);
                    if (two) atomicAdd(&hist[2 * NC * NK + c * NK + k0 + 1], c1);
                }
            }
        }
    }
    if (cl) atomicAdd(&scnt[0], cl);
    if (cf) atomicAdd(&scnt[1], cf);
    if (ce) atomicAdd(&scnt[2], ce);
    __syncthreads();

    int rep = bid & (REP - 1);
    float* gnum = wsf + NUM_OFF + ((rep * 2 + map) * NB + b) * GRP_SZ;
    for (int i = tid; i < GRP_SZ; i += 256) {
        float v = hist[i];
        if (v != 0.0f) atomicAdd(&gnum[i], v);
    }
    int* gcnt = wsi + CNT_OFF + ((rep * 2 + map) * NB + b) * 3;
    if (tid < 3 && scnt[tid]) atomicAdd(&gcnt[tid], scnt[tid]);
}

__global__ void k_final(const float* wsf, const int* wsi, float* out) {
    int tid = (int)threadIdx.x;   // 64 threads
    double part = 0.0;
    if (tid < NB * 3 * NC) {      // 36 items: (b, r, c)
        int b = tid / (3 * NC);
        int r = (tid / NC) % 3;
        int c = tid % NC;
        int ng = 0, nr = 0;
        for (int rp = 0; rp < REP; ++rp) {
            ng += wsi[CNT_OFF + ((rp * 2 + 0) * NB + b) * 3 + r];
            nr += wsi[CNT_OFF + ((rp * 2 + 1) * NB + b) * 3 + r];
        }
        if (ng > 0 && nr > 0) {
            float numg[NK], numr[NK];
            float Sg = 0.0f, Sr = 0.0f;
            for (int k = 0; k < NK; ++k) {
                float ag = 0.0f, ar = 0.0f;
                for (int rp = 0; rp < REP; ++rp) {
                    ag += wsf[NUM_OFF + ((rp * 2 + 0) * NB + b) * GRP_SZ + r * NC * NK + c * NK + k];
                    ar += wsf[NUM_OFF + ((rp * 2 + 1) * NB + b) * GRP_SZ + r * NC * NK + c * NK + k];
                }
                numg[k] = ag; numr[k] = ar;
                Sg += ag; Sr += ar;
            }
            float dg = (float)ng * Sg;
            float dr = (float)nr * Sr;
            dg = (dg > 0.0f) ? dg : 1.0f;
            dr = (dr > 0.0f) ? dr : 1.0f;
            double acc = 0.0;
            for (int k = 0; k < NK; ++k) {
                float hg = numg[k] / dg;
                float hr = numr[k] / dr;
                acc += fabs((double)hg - (double)hr);
            }
            double wgt = (r == 1) ? 0.1 : 1.0;
            part = wgt * acc / (double)NK;
        }
    }
    __shared__ double sred[64];
    sred[tid] = part;
    __syncthreads();
    for (int off = 32; off > 0; off >>= 1) {
        if (tid < off) sred[tid] += sred[tid + off];
        __syncthreads();
    }
    if (tid == 0) out[0] = (float)(sred[0] / (double)(NB * NC * 3));
}

extern "C" void kernel_launch(void* const* d_in, const int* in_sizes, int n_in,
                              void* d_out, int out_size, void* d_ws, size_t ws_size,
                              hipStream_t stream) {
    const float* gen    = (const float*)d_in[0];
    const float* realv  = (const float*)d_in[1];
    const int* seg_gen  = (const int*)d_in[2];
    const int* seg_real = (const int*)d_in[3];
    int*   wsi = (int*)d_ws;
    float* wsf = (float*)d_ws;

    k_init <<<dim3(32),                   dim3(256), 0, stream>>>(wsi, wsf);
    k_bbox <<<dim3(2 * NB * BBOX_CH),     dim3(256), 0, stream>>>(seg_gen, seg_real, wsi);
    k_hist <<<dim3(2 * NB * HIST_CH),     dim3(256), 0, stream>>>(gen, realv, seg_gen, seg_real, wsi, wsf);
    k_final<<<dim3(1),                    dim3(64),  0, stream>>>(wsf, wsi, (float*)d_out);
}

// Round 3
// 44.534 us; speedup vs baseline: 3.0365x; 3.0365x over previous
//
#include <hip/hip_runtime.h>

#define HH 512
#define WW 512
#define NB 4            // batch
#define NC 3            // channels
#define NK 33           // histogram grid points
#define SPC 0.0625f     // 2/32
#define REP 4           // global accumulator replicas
#define NREP 16         // LDS sub-histogram replicas
#define GRP_SZ (3*NC*NK)            // 297 = [region][channel][bin]

// workspace layout, in 4-byte words:
//   [0 .. 32)                       int   bbox[2][NB][4] {ymin,ymax,xmin,xmax}
//   [GCNT_OFF .. +9504)             uint  gcnt[REP][2][NB][297]
//   [GSUM_OFF .. +9504)             float gsum[REP][2][NB][297]
#define BBOX_OFF 0
#define GCNT_OFF 32
#define GCNT_SZ  (REP*2*NB*GRP_SZ)          // 9504
#define GSUM_OFF (GCNT_OFF + GCNT_SZ)       // 9536
#define WS_TOTAL (GSUM_OFF + GCNT_SZ)       // 19040 words (~76 KB)

__global__ void k_init(int* wsi) {
    int i = blockIdx.x * blockDim.x + threadIdx.x;
    for (; i < WS_TOTAL; i += gridDim.x * blockDim.x) {
        if (i < GCNT_OFF) {
            int v = i & 3;  // 0:ymin 1:ymax 2:xmin 3:xmax
            wsi[i] = (v == 0) ? HH : (v == 1) ? -1 : (v == 2) ? WW : -1;
        } else {
            wsi[i] = 0;     // uint/float zeros
        }
    }
}

#define BBOX_CH 64
__global__ void k_bbox(const int* __restrict__ seg_gen,
                       const int* __restrict__ seg_real,
                       int* wsi) {
    int bid = blockIdx.x;
    int map = bid / (NB * BBOX_CH);
    int rem = bid % (NB * BBOX_CH);
    int b = rem / BBOX_CH;
    int chunk = rem % BBOX_CH;
    const int* seg = (map == 0 ? seg_gen : seg_real) + b * HH * WW;
    const int PIX = HH * WW / BBOX_CH;       // 4096
    int base = chunk * PIX;
    int tid = (int)threadIdx.x;

    int ymin = HH, ymax = -1, xmin = WW, xmax = -1;
    #pragma unroll
    for (int it = 0; it < PIX / (256 * 4); ++it) {
        int p0 = base + (it * 256 + tid) * 4;
        int4 s4 = *(const int4*)&seg[p0];
        int h = p0 >> 9;
        int w0 = p0 & (WW - 1);
        int sv[4] = {s4.x, s4.y, s4.z, s4.w};
        #pragma unroll
        for (int j = 0; j < 4; ++j) {
            int s = sv[j];
            if (s == 4 || s == 5) {
                ymin = min(ymin, h); ymax = max(ymax, h);
                xmin = min(xmin, w0 + j); xmax = max(xmax, w0 + j);
            }
        }
    }
    __shared__ int sy0[256], sy1[256], sx0[256], sx1[256];
    sy0[tid] = ymin; sy1[tid] = ymax; sx0[tid] = xmin; sx1[tid] = xmax;
    __syncthreads();
    for (int off = 128; off > 0; off >>= 1) {
        if (tid < off) {
            sy0[tid] = min(sy0[tid], sy0[tid + off]);
            sy1[tid] = max(sy1[tid], sy1[tid + off]);
            sx0[tid] = min(sx0[tid], sx0[tid + off]);
            sx1[tid] = max(sx1[tid], sx1[tid + off]);
        }
        __syncthreads();
    }
    if (tid == 0) {
        int* bb = wsi + BBOX_OFF + (map * NB + b) * 4;
        atomicMin(&bb[0], sy0[0]);
        atomicMax(&bb[1], sy1[0]);
        atomicMin(&bb[2], sx0[0]);
        atomicMax(&bb[3], sx1[0]);
    }
}

#define HIST_CH 128
__global__ void k_hist(const float* __restrict__ gen,
                       const float* __restrict__ realv,
                       const int* __restrict__ seg_gen,
                       const int* __restrict__ seg_real,
                       int* wsi, unsigned int* wsu, float* wsf) {
    int bid = blockIdx.x;
    int map = bid / (NB * HIST_CH);
    int rem = bid % (NB * HIST_CH);
    int b = rem / HIST_CH;
    int chunk = rem % HIST_CH;
    const float* img = (map == 0 ? gen : realv);
    const int* seg = (map == 0 ? seg_gen : seg_real) + b * HH * WW;
    int tid = (int)threadIdx.x;
    int rp = tid & (NREP - 1);

    __shared__ unsigned int lh[NREP * GRP_SZ];   // 16 x 297 packed (cnt<<24 | fq)
    for (int i = tid; i < NREP * GRP_SZ; i += 256) lh[i] = 0u;

    // padded eye bbox (replicates reference, incl. the double-pad quirk)
    const int* bb = wsi + BBOX_OFF + (map * NB + b) * 4;
    int ymin0 = bb[0], ymax0 = bb[1], xmin0 = bb[2], xmax0 = bb[3];
    bool has = (ymax0 >= 0);
    int pady = (int)(0.15f * (float)(ymax0 - ymin0));
    int padx = (int)(0.15f * (float)(xmax0 - xmin0));
    int ymin = max(0, ymin0 - pady);
    int ymax = min(HH, ymax0 + pady);
    int xmin = max(0, xmin0 - padx);
    int xmax = min(WW, xmax0 + padx);
    ymax = min(HH - 1, ymax + pady);
    xmax = min(WW - 1, xmax + padx);
    __syncthreads();

    unsigned int* lhr = lh + rp * GRP_SZ;
    const int PIX = HH * WW / HIST_CH;    // 2048, 8 px/thread
    int base = chunk * PIX;
    #pragma unroll
    for (int it = 0; it < PIX / (256 * 4); ++it) {   // 2 iters
        int p0 = base + (it * 256 + tid) * 4;
        int4 s4 = *(const int4*)&seg[p0];
        int h = p0 >> 9;
        int w0 = p0 & (WW - 1);
        bool eyerow = has & (h >= ymin) & (h < ymax);
        int sv[4] = {s4.x, s4.y, s4.z, s4.w};
        bool lips[4], face[4], eye[4];
        #pragma unroll
        for (int j = 0; j < 4; ++j) {
            int s = sv[j];
            lips[j] = (s == 11) | (s == 12);
            face[j] = (s == 1);
            eye[j]  = eyerow & ((w0 + j) >= xmin) & ((w0 + j) < xmax);
        }
        #pragma unroll
        for (int c = 0; c < NC; ++c) {
            float4 v = *(const float4*)&img[((b * NC + c) << 18) + p0];
            float xv[4] = {v.x, v.y, v.z, v.w};
            #pragma unroll
            for (int j = 0; j < 4; ++j) {
                if (!(lips[j] | face[j] | eye[j])) continue;
                float t = (xv[j] + 1.0f) * 16.0f;
                int k0 = (int)t;
                k0 = min(max(k0, 0), NK - 1);
                float f = t - (float)k0;
                unsigned int pk = 0x1000000u | (unsigned int)(f * 4096.0f);
                int kc = c * NK + k0;
                if (lips[j]) atomicAdd(&lhr[0 * NC * NK + kc], pk);
                if (face[j]) atomicAdd(&lhr[1 * NC * NK + kc], pk);
                if (eye[j])  atomicAdd(&lhr[2 * NC * NK + kc], pk);
            }
        }
    }
    __syncthreads();

    // reduce 16 replicas -> (cnt, sumf), flush with global atomics (REP-spread)
    int rep = bid & (REP - 1);
    unsigned int* gcnt = wsu + GCNT_OFF + ((rep * 2 + map) * NB + b) * GRP_SZ;
    float*        gsum = wsf + GSUM_OFF + ((rep * 2 + map) * NB + b) * GRP_SZ;
    for (int i = tid; i < GRP_SZ; i += 256) {
        unsigned int cnt = 0, fq = 0;
        #pragma unroll
        for (int r = 0; r < NREP; ++r) {
            unsigned int v = lh[r * GRP_SZ + i];
            cnt += v >> 24;
            fq  += v & 0xFFFFFFu;
        }
        if (cnt) {
            atomicAdd(&gcnt[i], cnt);
            atomicAdd(&gsum[i], (float)fq * (1.0f / 4096.0f));
        }
    }
}

#define NITEM (2 * NB * GRP_SZ)   // 2376
__global__ void k_final(const unsigned int* wsu, const float* wsf, float* out) {
    int tid = (int)threadIdx.x;   // 1024 threads
    __shared__ float sC[NITEM], sF[NITEM], sNum[NITEM];
    __shared__ int   sN[2 * NB * 3];      // 24
    __shared__ float sS[2 * NB * NC * 3]; // 72
    __shared__ double sRed[1024];

    // Phase A: region pixel counts N[map][b][r] from c=0 slice
    if (tid < 24) {
        int map = tid / 12, b = (tid / 3) % NB, r = tid % 3;
        int n = 0;
        for (int rep = 0; rep < REP; ++rep) {
            const unsigned int* g = wsu + GCNT_OFF + ((rep * 2 + map) * NB + b) * GRP_SZ + r * NC * NK;
            for (int k = 0; k < NK; ++k) n += (int)g[k];
        }
        sN[tid] = n;
    }
    // Phase B: rep-summed cnt & sumf per item
    for (int i = tid; i < NITEM; i += 1024) {
        int map = i / (NB * GRP_SZ);
        int rem = i % (NB * GRP_SZ);
        int b = rem / GRP_SZ, idx = rem % GRP_SZ;
        float C = 0.0f, F = 0.0f;
        for (int rep = 0; rep < REP; ++rep) {
            int base = ((rep * 2 + map) * NB + b) * GRP_SZ + idx;
            C += (float)wsu[GCNT_OFF + base];
            F += wsf[GSUM_OFF + base];
        }
        sC[i] = C; sF[i] = F;
    }
    __syncthreads();
    // Phase C: num[k] = SPC*(cnt[k] - F[k] + F[k-1])
    for (int i = tid; i < NITEM; i += 1024) {
        int k = i % NK;
        float fp = (k > 0) ? sF[i - 1] : 0.0f;
        sNum[i] = fmaxf(SPC * ((sC[i] - sF[i]) + fp), 0.0f);
    }
    __syncthreads();
    // Phase D: S per (map,b,r,c)
    if (tid < 72) {
        float s = 0.0f;
        const float* p = sNum + tid * NK;
        for (int k = 0; k < NK; ++k) s += p[k];
        sS[tid] = s;
    }
    __syncthreads();
    // Phase E: l1 terms
    double acc = 0.0;
    for (int j = tid; j < NB * GRP_SZ; j += 1024) {   // 1188 (b, r, c, k)
        int b = j / GRP_SZ, idx = j % GRP_SZ;
        int r = idx / (NC * NK);
        int c = (idx / NK) % NC;
        int ng = sN[b * 3 + r];
        int nr = sN[12 + b * 3 + r];
        if (ng > 0 && nr > 0) {
            int iG = j, iR = NB * GRP_SZ + j;
            float dg = (float)ng * sS[(b * 3 + r) * NC + c];
            float dr = (float)nr * sS[(NB * 3 + b * 3 + r) * NC + c];
            dg = (dg > 0.0f) ? dg : 1.0f;
            dr = (dr > 0.0f) ? dr : 1.0f;
            double d = fabs((double)(sNum[iG] / dg) - (double)(sNum[iR] / dr));
            acc += ((r == 1) ? 0.1 : 1.0) * d;
        }
    }
    sRed[tid] = acc;
    __syncthreads();
    for (int off = 512; off > 0; off >>= 1) {
        if (tid < off) sRed[tid] += sRed[tid + off];
        __syncthreads();
    }
    if (tid == 0) out[0] = (float)(sRed[0] / (double)(NK) / (double)(NB * NC * 3));
}

extern "C" void kernel_launch(void* const* d_in, const int* in_sizes, int n_in,
                              void* d_out, int out_size, void* d_ws, size_t ws_size,
                              hipStream_t stream) {
    const float* gen    = (const float*)d_in[0];
    const float* realv  = (const float*)d_in[1];
    const int* seg_gen  = (const int*)d_in[2];
    const int* seg_real = (const int*)d_in[3];
    int*          wsi = (int*)d_ws;
    unsigned int* wsu = (unsigned int*)d_ws;
    float*        wsf = (float*)d_ws;

    k_init <<<dim3(32),                dim3(256),  0, stream>>>(wsi);
    k_bbox <<<dim3(2 * NB * BBOX_CH),  dim3(256),  0, stream>>>(seg_gen, seg_real, wsi);
    k_hist <<<dim3(2 * NB * HIST_CH),  dim3(256),  0, stream>>>(gen, realv, seg_gen, seg_real, wsi, wsu, wsf);
    k_final<<<dim3(1),                 dim3(1024), 0, stream>>>(wsu, wsf, (float*)d_out);
}

// Round 4
// 43.490 us; speedup vs baseline: 3.1095x; 1.0240x over previous
//
#include <hip/hip_runtime.h>

#define HH 512
#define WW 512
#define NB 4            // batch
#define NC 3            // channels
#define NK 33           // histogram grid points
#define SPC 0.0625f     // 2/32
#define REP 4           // global accumulator replicas
#define NREP 16         // LDS sub-histogram replicas
#define GRP_SZ (3*NC*NK)            // 297 = [region][channel][bin]
#define BBOX_CH 64
#define HIST_CH 128
#define NBLK_BBOX (2*NB*BBOX_CH)    // 512
#define NBLK_HIST (2*NB*HIST_CH)    // 1024

// workspace layout (4-byte words):
//   [0 .. 2048)        int4 bbp[512]  partial bboxes {ymin,ymax,xmin,xmax}
//   [2048]             uint ticket
//   [2056 .. +9504)    uint gcnt[REP][2][NB][297]
//   [GSUM .. +9504)    float gsum[REP][2][NB][297]
#define BBP_OFF    0
#define TICKET_OFF 2048
#define GCNT_OFF   2056
#define GCNT_SZ    (REP*2*NB*GRP_SZ)        // 9504
#define GSUM_OFF   (GCNT_OFF + GCNT_SZ)     // 11560
#define WS_TOTAL   (GSUM_OFF + GCNT_SZ)     // 21064 words (~84 KB)
#define ZERO_SZ    (WS_TOTAL - TICKET_OFF)  // 19016
#define ZERO_PER   ((ZERO_SZ + NBLK_BBOX - 1) / NBLK_BBOX)   // 38

__global__ __launch_bounds__(256) void k_bbox(const int* __restrict__ seg_gen,
                                              const int* __restrict__ seg_real,
                                              int* __restrict__ ws) {
    int bid = blockIdx.x, tid = (int)threadIdx.x;

    // cooperative zero of ticket + gcnt + gsum (plain stores; visible at kernel boundary)
    int zbase = TICKET_OFF + bid * ZERO_PER;
    for (int i = tid; i < ZERO_PER; i += 256) {
        int idx = zbase + i;
        if (idx < WS_TOTAL) ws[idx] = 0;
    }

    int map = bid / (NB * BBOX_CH);
    int rem = bid % (NB * BBOX_CH);
    int b = rem / BBOX_CH, chunk = rem % BBOX_CH;
    const int4* seg4 = (const int4*)((map == 0 ? seg_gen : seg_real) + b * HH * WW);
    int base4 = chunk * (4096 / 4);          // 1024 int4 per chunk

    int4 v[4];
    #pragma unroll
    for (int it = 0; it < 4; ++it) v[it] = seg4[base4 + it * 256 + tid];

    int ymin = HH, ymax = -1, xmin = WW, xmax = -1;
    #pragma unroll
    for (int it = 0; it < 4; ++it) {
        int p0 = (base4 + it * 256 + tid) * 4;
        int h = p0 >> 9, w0 = p0 & (WW - 1);
        int sv[4] = {v[it].x, v[it].y, v[it].z, v[it].w};
        #pragma unroll
        for (int j = 0; j < 4; ++j) {
            int s = sv[j];
            if (s == 4 || s == 5) {
                ymin = min(ymin, h); ymax = max(ymax, h);
                xmin = min(xmin, w0 + j); xmax = max(xmax, w0 + j);
            }
        }
    }
    __shared__ int sy0[256], sy1[256], sx0[256], sx1[256];
    sy0[tid] = ymin; sy1[tid] = ymax; sx0[tid] = xmin; sx1[tid] = xmax;
    __syncthreads();
    for (int off = 128; off > 0; off >>= 1) {
        if (tid < off) {
            sy0[tid] = min(sy0[tid], sy0[tid + off]);
            sy1[tid] = max(sy1[tid], sy1[tid + off]);
            sx0[tid] = min(sx0[tid], sx0[tid + off]);
            sx1[tid] = max(sx1[tid], sx1[tid + off]);
        }
        __syncthreads();
    }
    if (tid == 0)
        ((int4*)ws)[BBP_OFF / 4 + bid] = make_int4(sy0[0], sy1[0], sx0[0], sx1[0]);
}

__global__ __launch_bounds__(256) void k_hist(const float* __restrict__ gen,
                                              const float* __restrict__ realv,
                                              const int* __restrict__ seg_gen,
                                              const int* __restrict__ seg_real,
                                              int* __restrict__ ws,
                                              float* __restrict__ out) {
    int bid = blockIdx.x, tid = (int)threadIdx.x;
    int map = bid / (NB * HIST_CH);
    int rem = bid % (NB * HIST_CH);
    int b = rem / HIST_CH, chunk = rem % HIST_CH;
    const float* img = (map == 0 ? gen : realv);
    const int* seg = (map == 0 ? seg_gen : seg_real) + b * HH * WW;

    // LDS: hist replicas (phase 1) aliased with finalize arrays (phase 2)
    __shared__ unsigned smem[7736];          // 30944 B
    unsigned* lh = smem;                     // [NREP*GRP_SZ] = 4752 packed u32
    __shared__ int sbb[5];                   // ymin,ymax,xmin,xmax,has
    __shared__ int slast;

    for (int i = tid; i < NREP * GRP_SZ; i += 256) lh[i] = 0u;

    // reduce 64 partial bboxes for this (map,b) with a wave-0 shfl reduce
    if (tid < 64) {
        int4 v = ((const int4*)ws)[BBP_OFF / 4 + (map * NB + b) * BBOX_CH + tid];
        #pragma unroll
        for (int off = 32; off > 0; off >>= 1) {
            v.x = min(v.x, __shfl_xor(v.x, off));
            v.y = max(v.y, __shfl_xor(v.y, off));
            v.z = min(v.z, __shfl_xor(v.z, off));
            v.w = max(v.w, __shfl_xor(v.w, off));
        }
        if (tid == 0) {
            int ymin0 = v.x, ymax0 = v.y, xmin0 = v.z, xmax0 = v.w;
            int has = (ymax0 >= 0);
            int pady = (int)(0.15f * (float)(ymax0 - ymin0));
            int padx = (int)(0.15f * (float)(xmax0 - xmin0));
            int ymin = max(0, ymin0 - pady);
            int ymaxv = min(HH, ymax0 + pady);
            int xminv = max(0, xmin0 - padx);
            int xmaxv = min(WW, xmax0 + padx);
            ymaxv = min(HH - 1, ymaxv + pady);   // double-pad quirk
            xmaxv = min(WW - 1, xmaxv + padx);
            sbb[0] = ymin; sbb[1] = ymaxv; sbb[2] = xminv; sbb[3] = xmaxv; sbb[4] = has;
        }
    }
    __syncthreads();
    int bbym = sbb[0], bbyM = sbb[1], bbxm = sbb[2], bbxM = sbb[3], has = sbb[4];

    // ---- main pass: 2048 px/block, 8 px/thread, all loads hoisted ----
    unsigned* lhr = lh + (tid & (NREP - 1)) * GRP_SZ;
    int q0 = chunk * (2048 / 4) + tid;       // int4 index, group A
    int q1 = q0 + 256;                       // group B
    const int4* seg4 = (const int4*)seg;
    int4 sA = seg4[q0], sB = seg4[q1];
    const float4* i4 = (const float4*)img + ((size_t)(b * NC) << 16);
    float4 fA0 = i4[(0 << 16) + q0], fA1 = i4[(1 << 16) + q0], fA2 = i4[(2 << 16) + q0];
    float4 fB0 = i4[(0 << 16) + q1], fB1 = i4[(1 << 16) + q1], fB2 = i4[(2 << 16) + q1];

    #pragma unroll
    for (int g = 0; g < 2; ++g) {
        int p = (g == 0 ? q0 : q1) * 4;
        int4 s4 = (g == 0) ? sA : sB;
        float xs0[4], xs1[4], xs2[4];
        { float4 f = (g == 0) ? fA0 : fB0; xs0[0]=f.x; xs0[1]=f.y; xs0[2]=f.z; xs0[3]=f.w; }
        { float4 f = (g == 0) ? fA1 : fB1; xs1[0]=f.x; xs1[1]=f.y; xs1[2]=f.z; xs1[3]=f.w; }
        { float4 f = (g == 0) ? fA2 : fB2; xs2[0]=f.x; xs2[1]=f.y; xs2[2]=f.z; xs2[3]=f.w; }
        int h = p >> 9, w0 = p & (WW - 1);
        bool eyerow = has && (h >= bbym) && (h < bbyM);
        int sv[4] = {s4.x, s4.y, s4.z, s4.w};
        #pragma unroll
        for (int j = 0; j < 4; ++j) {
            int s = sv[j];
            bool lips = (s == 11) | (s == 12);
            bool face = (s == 1);
            bool eye  = eyerow & ((w0 + j) >= bbxm) & ((w0 + j) < bbxM);
            if (!(lips | face | eye)) continue;
            #pragma unroll
            for (int c = 0; c < NC; ++c) {
                float x = (c == 0) ? xs0[j] : (c == 1) ? xs1[j] : xs2[j];
                float t = (x + 1.0f) * 16.0f;
                int k0 = (int)t;
                k0 = min(max(k0, 0), NK - 1);
                float f = t - (float)k0;
                unsigned pk = 0x1000000u | (unsigned)(f * 4096.0f);
                int kc = c * NK + k0;
                if (lips) atomicAdd(&lhr[kc], pk);
                if (face) atomicAdd(&lhr[1 * NC * NK + kc], pk);
                if (eye)  atomicAdd(&lhr[2 * NC * NK + kc], pk);
            }
        }
    }
    __syncthreads();

    // ---- flush: 16 replicas -> packed (cnt, sumf) -> global atomics ----
    int rep = bid & (REP - 1);
    unsigned* gcnt = (unsigned*)ws + GCNT_OFF + ((rep * 2 + map) * NB + b) * GRP_SZ;
    float*    gsum = (float*)ws + GSUM_OFF + ((rep * 2 + map) * NB + b) * GRP_SZ;
    for (int i = tid; i < GRP_SZ; i += 256) {
        unsigned cnt = 0, fq = 0;
        #pragma unroll
        for (int r = 0; r < NREP; ++r) {
            unsigned v = lh[r * GRP_SZ + i];
            cnt += v >> 24;
            fq  += v & 0xFFFFFFu;
        }
        if (cnt) {
            atomicAdd(&gcnt[i], cnt);
            atomicAdd(&gsum[i], (float)fq * (1.0f / 4096.0f));
        }
    }
    __syncthreads();          // drains flush atomics (vmcnt 0 before barrier)

    // ---- last-block finalize ----
    if (tid == 0) {
        __threadfence();
        unsigned t = atomicAdd((unsigned*)ws + TICKET_OFF, 1u);
        slast = (t == NBLK_HIST - 1);
    }
    __syncthreads();
    if (!slast) return;
    __threadfence();          // acquire: each wave invalidates before loading

    float* sC   = (float*)smem;              // [2376]
    float* sF   = sC + 2 * NB * GRP_SZ;      // [2376]
    float* sNum = sF + 2 * NB * GRP_SZ;      // [2376]
    int*   sN   = (int*)(smem + 7128);       // [24]
    float* sS   = (float*)(smem + 7152);     // [72]
    double* sRed = (double*)(smem + 7224);   // [256]

    const unsigned* gcntAll = (const unsigned*)ws + GCNT_OFF;
    const float*    gsumAll = (const float*)ws + GSUM_OFF;
    const int NITEM = 2 * NB * GRP_SZ;       // 2376
    for (int i = tid; i < NITEM; i += 256) {
        int mp = i / (NB * GRP_SZ);
        int r2 = i % (NB * GRP_SZ);
        int b2 = r2 / GRP_SZ, idx = r2 % GRP_SZ;
        float C = 0.0f, F = 0.0f;
        #pragma unroll
        for (int rp = 0; rp < REP; ++rp) {
            int off = ((rp * 2 + mp) * NB + b2) * GRP_SZ + idx;
            C += (float)gcntAll[off];
            F += gsumAll[off];
        }
        sC[i] = C; sF[i] = F;
    }
    __syncthreads();
    if (tid < 24) {           // N[map][b][r] from channel-0 counts
        int mp = tid / 12, b2 = (tid / 3) % NB, r = tid % 3;
        const float* p = sC + (mp * NB + b2) * GRP_SZ + r * (NC * NK);
        float n = 0.0f;
        for (int k = 0; k < NK; ++k) n += p[k];
        sN[tid] = (int)(n + 0.5f);
    }
    for (int i = tid; i < NITEM; i += 256) {
        int k = i % NK;
        float fp = (k > 0) ? sF[i - 1] : 0.0f;
        sNum[i] = fmaxf(SPC * ((sC[i] - sF[i]) + fp), 0.0f);
    }
    __syncthreads();
    if (tid < 72) {
        float s = 0.0f;
        const float* p = sNum + tid * NK;
        for (int k = 0; k < NK; ++k) s += p[k];
        sS[tid] = s;
    }
    __syncthreads();
    double acc = 0.0;
    for (int j = tid; j < NB * GRP_SZ; j += 256) {   // 1188 (b, r, c, k)
        int b2 = j / GRP_SZ, idx = j % GRP_SZ;
        int r = idx / (NC * NK);
        int c = (idx / NK) % NC;
        int ng = sN[b2 * 3 + r];
        int nr = sN[12 + b2 * 3 + r];
        if (ng > 0 && nr > 0) {
            int g = b2 * 9 + r * 3 + c;              // sS group index within a map
            float dg = (float)ng * sS[g];
            float dr = (float)nr * sS[36 + g];
            dg = (dg > 0.0f) ? dg : 1.0f;
            dr = (dr > 0.0f) ? dr : 1.0f;
            double d = fabs((double)(sNum[j] / dg) - (double)(sNum[NB * GRP_SZ + j] / dr));
            acc += ((r == 1) ? 0.1 : 1.0) * d;
        }
    }
    sRed[tid] = acc;
    __syncthreads();
    for (int off = 128; off > 0; off >>= 1) {
        if (tid < off) sRed[tid] += sRed[tid + off];
        __syncthreads();
    }
    if (tid == 0) out[0] = (float)(sRed[0] / (double)NK / (double)(NB * NC * 3));
}

extern "C" void kernel_launch(void* const* d_in, const int* in_sizes, int n_in,
                              void* d_out, int out_size, void* d_ws, size_t ws_size,
                              hipStream_t stream) {
    const float* gen    = (const float*)d_in[0];
    const float* realv  = (const float*)d_in[1];
    const int* seg_gen  = (const int*)d_in[2];
    const int* seg_real = (const int*)d_in[3];
    int* wsi = (int*)d_ws;

    k_bbox<<<dim3(NBLK_BBOX), dim3(256), 0, stream>>>(seg_gen, seg_real, wsi);
    k_hist<<<dim3(NBLK_HIST), dim3(256), 0, stream>>>(gen, realv, seg_gen, seg_real,
                                                      wsi, (float*)d_out);
}